// Round 5
// baseline (134.900 us; speedup 1.0000x reference)
//
#include <hip/hip_runtime.h>
#include <hip/hip_bf16.h>
#include <math.h>

// Problem constants (fixed by setup_inputs)
#define M_TOT 2
#define N_TOT 4096
#define DZ    64
#define G_TOT 16384

// Tiling: 128-thread blocks (2 waves), each wave owns 64 g-rows (4 A-frag groups).
#define BG      128
#define BN      64
#define THREADS 128
#define NSPLIT  4
#define NCHUNK  (N_TOT / NSPLIT)   // 1024
#define ITERS   (NCHUNK / BN)      // 16
// zT: bf16 [dz=64][n=64], row = 128 B. 3-bit XOR swizzle of the 16B block:
// phys_block = logical_block ^ ((row>>1)&7). Staging writes (b128) and B-frag
// reads (b128) both land at the 8-dword/bank b128 floor (bank arithmetic in
// journal). k-order inside 16B blocks preserved -> MFMA A/B correspondence OK.
#define ZROW_B  128
#define ZT_B    (DZ * ZROW_B)      // 8192
#define KX_OFS  ZT_B               // 8192
#define KY_OFS  (KX_OFS + BN * 4)  // 8448
#define HK_OFS  (KY_OFS + BN * 4)  // 8704
#define BUF_B   (HK_OFS + BN * 4)  // 8960 bytes per pipeline buffer

typedef __attribute__((ext_vector_type(8))) short  short8;  // 8 bf16 MFMA A/B frag
typedef __attribute__((ext_vector_type(4))) float  f32x4;   // MFMA C/D frag
typedef __attribute__((ext_vector_type(2))) float  f32x2;   // packed fp32 (v_pk_*_f32)
typedef __attribute__((ext_vector_type(4))) int    int4v;
typedef __attribute__((ext_vector_type(4))) unsigned int uint4v;

#if __has_builtin(__builtin_amdgcn_cvt_pk_bf16_f32)
__device__ __forceinline__ unsigned int pack_bf16_pair(float lo, float hi) {
    return __builtin_bit_cast(unsigned int, __builtin_amdgcn_cvt_pk_bf16_f32(lo, hi));
}
#else
__device__ __forceinline__ unsigned int pack_bf16_pair(float lo, float hi) {
    const unsigned int a = __float_as_uint(lo) + 0x8000u;  // round-half-up to bf16
    const unsigned int b = __float_as_uint(hi) + 0x8000u;
    return __builtin_amdgcn_perm(b, a, 0x07060302u);       // [lo[31:16], hi[31:16]]
}
#endif

__global__ __launch_bounds__(THREADS, 2)
void setconv_kernel(const float* __restrict__ x,       // [2][4096][2]
                    const float* __restrict__ z,       // [2][4096][64]
                    const float* __restrict__ x_grid,  // [2][16384][2]
                    const float* __restrict__ z_grid,  // [2][16384][64]
                    const float* __restrict__ lsp,     // [2]
                    float* __restrict__ out)           // [2][16384][64], memset to 0
{
    __shared__ __align__(16) unsigned char lds[2 * BUF_B];

    const int tid  = threadIdx.x;
    const int wave = tid >> 6;
    const int lane = tid & 63;
    const int quad = lane >> 4;
    const int l16  = lane & 15;

    const int mb    = blockIdx.y;
    const int gbase = blockIdx.x * BG;
    const int nbase = blockIdx.z * NCHUNK;

    const float LOG2E = 1.44269504088896340736f;
    const float inv0 = 1.0f / (1e-5f + log1pf(__expf(lsp[0])));
    const float inv1 = 1.0f / (1e-5f + log1pf(__expf(lsp[1])));

    // 4 row-groups per wave: rows wave*64 + g*16 + l16.
    f32x2 qx2[4], qy2[4], hq2[4];
#pragma unroll
    for (int g = 0; g < 4; g++) {
        const int grow = gbase + wave * 64 + g * 16 + l16;
        const float2 qraw = *(const float2*)&x_grid[(size_t)(mb * G_TOT + grow) * 2];
        const float qx = qraw.x * inv0, qy = qraw.y * inv1;
        const float qxL = LOG2E * qx, qyL = LOG2E * qy;
        const float hq  = -0.5f * LOG2E * (qx * qx + qy * qy);
        qx2[g] = (f32x2){qxL, qxL};
        qy2[g] = (f32x2){qyL, qyL};
        hq2[g] = (f32x2){hq, hq};
    }

    // Staging: sdzg = dz-group of 4 (consecutive lanes -> consecutive dz ->
    // 256B-coalesced float4 global loads), snq = n-octet (n = snq*8 + j).
    const int sdzg = tid & 15;
    const int snq  = tid >> 4;     // 0..7
    const float* zb = z + (size_t)mb * N_TOT * DZ + sdzg * 4;
    // Per-i write offsets: row d = sdzg*4+i, logical block = snq,
    // phys = snq ^ ((2*(sdzg&3) + (i>>1)) & 7).
    unsigned wr_off[4];
#pragma unroll
    for (int i = 0; i < 4; i++) {
        const unsigned phys = ((unsigned)snq ^ ((2u * (sdzg & 3) + (i >> 1)) & 7u));
        wr_off[i] = (unsigned)(sdzg * 4 + i) * ZROW_B + phys * 16;
    }

    // B-frag read bases: row r = nt*16+l16 -> swz = (l16>>1)&7; block kc*4+quad.
    const unsigned swz_l = (unsigned)((l16 >> 1) & 7);
    const unsigned q0    = (unsigned)quad ^ swz_l;
    const unsigned rbA   = (unsigned)l16 * ZROW_B + q0 * 16;         // kc = 0
    const unsigned rbB   = (unsigned)l16 * ZROW_B + (q0 ^ 4u) * 16;  // kc = 1

    f32x4 acc[4][4];
#pragma unroll
    for (int g = 0; g < 4; g++)
#pragma unroll
        for (int i = 0; i < 4; i++) acc[g][i] = (f32x4){0.f, 0.f, 0.f, 0.f};

    auto stage = [&](unsigned dst, const float4* zf, float2 kraw) {
#pragma unroll
        for (int i = 0; i < 4; i++) {
            uint4v w;
            w.x = pack_bf16_pair(zf[0][i], zf[1][i]);
            w.y = pack_bf16_pair(zf[2][i], zf[3][i]);
            w.z = pack_bf16_pair(zf[4][i], zf[5][i]);
            w.w = pack_bf16_pair(zf[6][i], zf[7][i]);
            *(uint4v*)(lds + dst + wr_off[i]) = w;
        }
        if (wave == 0) {  // lanes 0..63 stage the 64 k-points
            const float kx = kraw.x * inv0, ky = kraw.y * inv1;
            *(float*)(lds + dst + KX_OFS + lane * 4) = kx;
            *(float*)(lds + dst + KY_OFS + lane * 4) = ky;
            *(float*)(lds + dst + HK_OFS + lane * 4) = -0.5f * LOG2E * (kx * kx + ky * ky);
        }
    };

    // ---- prologue: fetch + stage tile 0 into buffer 0 ----
    {
        float4 zf[8];
        float2 kraw = {0.f, 0.f};
        const float* zp = zb + (size_t)(nbase + snq * 8) * DZ;
#pragma unroll
        for (int j = 0; j < 8; j++) zf[j] = *(const float4*)(zp + j * DZ);
        if (wave == 0) kraw = *(const float2*)(x + (size_t)(mb * N_TOT + nbase + lane) * 2);
        stage(0u, zf, kraw);
    }
    __syncthreads();

    for (int t = 0; t < ITERS; t++) {
        const unsigned bo = (unsigned)((t & 1) ? BUF_B : 0);
        const unsigned bn = bo ^ (unsigned)BUF_B;

        // ---- issue next tile's global loads (latency hidden under compute) ----
        float4 zf[8];
        float2 kraw = {0.f, 0.f};
        if (t + 1 < ITERS) {
            const int nb1 = nbase + (t + 1) * BN;
            const float* zp = zb + (size_t)(nb1 + snq * 8) * DZ;
#pragma unroll
            for (int j = 0; j < 8; j++) zf[j] = *(const float4*)(zp + j * DZ);
            if (wave == 0) kraw = *(const float2*)(x + (size_t)(mb * N_TOT + nb1 + lane) * 2);
        }

        // ---- compute tile t from buffer bo ----
#pragma unroll
        for (int kc = 0; kc < 2; kc++) {
            // k-data for this quad's 8 n (two packed pairs per float4)
            const unsigned kb = bo + (unsigned)(kc * 128 + quad * 32);
            const float4 kxa = *(const float4*)(lds + kb + KX_OFS);
            const float4 kxb = *(const float4*)(lds + kb + KX_OFS + 16);
            const float4 kya = *(const float4*)(lds + kb + KY_OFS);
            const float4 kyb = *(const float4*)(lds + kb + KY_OFS + 16);
            const float4 hka = *(const float4*)(lds + kb + HK_OFS);
            const float4 hkb = *(const float4*)(lds + kb + HK_OFS + 16);
            const f32x2 kx2[4] = {{kxa.x, kxa.y}, {kxa.z, kxa.w}, {kxb.x, kxb.y}, {kxb.z, kxb.w}};
            const f32x2 ky2[4] = {{kya.x, kya.y}, {kya.z, kya.w}, {kyb.x, kyb.y}, {kyb.z, kyb.w}};
            const f32x2 hk2[4] = {{hka.x, hka.y}, {hka.z, hka.w}, {hkb.x, hkb.y}, {hkb.z, hkb.w}};

            // B-frags once per kc, reused by all 4 row-groups.
            short8 bf[4];
            const unsigned rb = bo + ((kc == 0) ? rbA : rbB);
#pragma unroll
            for (int nt = 0; nt < 4; nt++)
                bf[nt] = *(const short8*)(lds + rb + nt * (16 * ZROW_B));

#pragma unroll
            for (int g = 0; g < 4; g++) {
                unsigned aw[4];
#pragma unroll
                for (int p = 0; p < 4; p++) {
                    f32x2 s = hq2[g] + hk2[p];                      // v_pk_add_f32
                    s = __builtin_elementwise_fma(qy2[g], ky2[p], s); // v_pk_fma_f32
                    s = __builtin_elementwise_fma(qx2[g], kx2[p], s); // v_pk_fma_f32
                    aw[p] = pack_bf16_pair(__builtin_amdgcn_exp2f(s.x),
                                           __builtin_amdgcn_exp2f(s.y));
                }
                const int4v  av = {(int)aw[0], (int)aw[1], (int)aw[2], (int)aw[3]};
                const short8 af = __builtin_bit_cast(short8, av);
#pragma unroll
                for (int nt = 0; nt < 4; nt++)
                    acc[g][nt] = __builtin_amdgcn_mfma_f32_16x16x32_bf16(af, bf[nt], acc[g][nt], 0, 0, 0);
            }
        }

        // ---- stage next tile into buffer bn; single barrier per iteration ----
        if (t + 1 < ITERS) {
            stage(bn, zf, kraw);
            __syncthreads();
        }
    }

    // ---- epilogue: C/D layout col = lane&15 (dz), row = quad*4 + reg (g-row) ----
    // out was memset to 0; all 4 n-splits atomicAdd. Split 0 folds z_grid in.
    const bool add_zg = (blockIdx.z == 0);
#pragma unroll
    for (int g = 0; g < 4; g++) {
        const int gout = gbase + wave * 64 + g * 16 + quad * 4;
#pragma unroll
        for (int nt = 0; nt < 4; nt++) {
#pragma unroll
            for (int r = 0; r < 4; r++) {
                const size_t idx = (size_t)(mb * G_TOT + gout + r) * DZ + nt * 16 + l16;
                const float v = add_zg ? (acc[g][nt][r] + z_grid[idx]) : acc[g][nt][r];
                atomicAdd(&out[idx], v);
            }
        }
    }
}

extern "C" void kernel_launch(void* const* d_in, const int* in_sizes, int n_in,
                              void* d_out, int out_size, void* d_ws, size_t ws_size,
                              hipStream_t stream) {
    const float* x   = (const float*)d_in[0];
    const float* z   = (const float*)d_in[1];
    const float* xg  = (const float*)d_in[2];
    const float* zgr = (const float*)d_in[3];
    const float* lsp = (const float*)d_in[4];
    float* out = (float*)d_out;

    // out = 0 (write-only memset node; z_grid folded in by split 0's atomics)
    hipMemsetAsync(out, 0, sizeof(float) * (size_t)M_TOT * G_TOT * DZ, stream);

    dim3 grid(G_TOT / BG, M_TOT, NSPLIT);
    setconv_kernel<<<grid, THREADS, 0, stream>>>(x, z, xg, zgr, lsp, out);
}